// Round 13
// baseline (382.391 us; speedup 1.0000x reference)
//
#include <hip/hip_runtime.h>
#include <hip/hip_fp16.h>

#define B_ 64
#define L_ 512
#define T_ 128
#define NTHR 128    // 2 waves; one tag j per thread; G=2 batches per block

typedef _Float16 h2v __attribute__((ext_vector_type(2)));
typedef __fp16   h2b __attribute__((ext_vector_type(2)));
typedef unsigned int u32x4 __attribute__((ext_vector_type(4)));

__device__ __forceinline__ float dot2_acc(unsigned int e, unsigned int a, float c) {
#if __has_builtin(__builtin_amdgcn_fdot2)
    h2v ev = __builtin_bit_cast(h2v, e);
    h2v av = __builtin_bit_cast(h2v, a);
    return __builtin_amdgcn_fdot2(ev, av, c, false);
#else
    __half2 eh = __builtin_bit_cast(__half2, e);
    __half2 ah = __builtin_bit_cast(__half2, a);
    float2 ef = __half22float2(eh), af = __half22float2(ah);
    return c + ef.x * af.x + ef.y * af.y;
#endif
}

__device__ __forceinline__ unsigned int pack2(float a, float b) {
#if __has_builtin(__builtin_amdgcn_cvt_pkrtz)
    h2b h = __builtin_amdgcn_cvt_pkrtz(a, b);
    return __builtin_bit_cast(unsigned int, h);
#else
    __half2 h = __floats2half2_rn(a, b);
    return __builtin_bit_cast(unsigned int, h);
#endif
}

// ---- pure-VALU wave-64 sum via DPP; total lands in lane 63 ----
template <int CTRL, int RMASK>
__device__ __forceinline__ float dpp_add(float v) {
    int t = __builtin_amdgcn_update_dpp(0, __builtin_bit_cast(int, v),
                                        CTRL, RMASK, 0xf, true);
    return v + __builtin_bit_cast(float, t);
}
__device__ __forceinline__ float wave_sum_lane63(float v) {
    v = dpp_add<0x111, 0xf>(v);   // row_shr:1
    v = dpp_add<0x112, 0xf>(v);   // row_shr:2
    v = dpp_add<0x114, 0xf>(v);   // row_shr:4
    v = dpp_add<0x118, 0xf>(v);   // row_shr:8
    v = dpp_add<0x142, 0xa>(v);   // row_bcast:15
    v = dpp_add<0x143, 0xc>(v);   // row_bcast:31 -> lane 63 = wave total
    return v;
}

__global__ __launch_bounds__(NTHR, 1) void crf_nll_kernel(
        const float* __restrict__ feats,   // [B, L, T]
        const float* __restrict__ trans,   // [T, T]
        const int*   __restrict__ tags,    // [B, L]
        const int*   __restrict__ mask,    // [B, L]
        float*       __restrict__ out)     // [B]
{
    __shared__ __align__(16) __half xbuf[2][2][T_];   // [dbuf][batch][j]
    __shared__ __align__(16) float  Shalf[2][2][2];   // [dbuf][batch][wave]
    __shared__ __align__(16) float  redx[8];

    const int tid  = threadIdx.x;
    const int lane = tid & 63;
    const int w    = tid >> 6;
    const int j    = tid;                 // this thread's tag column
    const int bA   = blockIdx.x * 2;
    const int bB   = bA + 1;

    const float* featA = feats + (size_t)bA * L_ * T_;
    const float* featB = feats + (size_t)bB * L_ * T_;
    const int*   maskA = mask + bA * L_;
    const int*   maskB = mask + bB * L_;

    // ---- E column j in registers: 16 named u32x4 = 64 VGPR (f16x2 over i-pairs) ----
    u32x4 ec_0, ec_1, ec_2, ec_3, ec_4, ec_5, ec_6, ec_7,
          ec_8, ec_9, ec_10, ec_11, ec_12, ec_13, ec_14, ec_15;
#define INIT_Q(k) { \
        float r0 = trans[(8 * (k) + 0) * T_ + j]; \
        float r1 = trans[(8 * (k) + 1) * T_ + j]; \
        float r2 = trans[(8 * (k) + 2) * T_ + j]; \
        float r3 = trans[(8 * (k) + 3) * T_ + j]; \
        float r4 = trans[(8 * (k) + 4) * T_ + j]; \
        float r5 = trans[(8 * (k) + 5) * T_ + j]; \
        float r6 = trans[(8 * (k) + 6) * T_ + j]; \
        float r7 = trans[(8 * (k) + 7) * T_ + j]; \
        ec_##k.x = pack2(__expf(r0), __expf(r1)); \
        ec_##k.y = pack2(__expf(r2), __expf(r3)); \
        ec_##k.z = pack2(__expf(r4), __expf(r5)); \
        ec_##k.w = pack2(__expf(r6), __expf(r7)); }
    INIT_Q(0)  INIT_Q(1)  INIT_Q(2)  INIT_Q(3)
    INIT_Q(4)  INIT_Q(5)  INIT_Q(6)  INIT_Q(7)
    INIT_Q(8)  INIT_Q(9)  INIT_Q(10) INIT_Q(11)
    INIT_Q(12) INIT_Q(13) INIT_Q(14) INIT_Q(15)
#undef INIT_Q

    // ---- init: alpha_0 = emit_0 for both batches ----
    float e0A = featA[j];
    float e0B = featB[j];
    {
        float vA = e0A, vB = e0B;
        #pragma unroll
        for (int off = 32; off >= 1; off >>= 1) {
            vA = fmaxf(vA, __shfl_xor(vA, off));
            vB = fmaxf(vB, __shfl_xor(vB, off));
        }
        if (lane == 0) { redx[w] = vA; redx[2 + w] = vB; }
    }
    __syncthreads();
    const float m0A = fmaxf(redx[0], redx[1]);
    const float m0B = fmaxf(redx[2], redx[3]);
    float xcA = __expf(e0A - m0A);
    float xcB = __expf(e0B - m0B);
    float NA = m0A, NB = m0B;
    xbuf[0][0][j] = __float2half(xcA);
    xbuf[0][1][j] = __float2half(xcB);
    {
        float sA = wave_sum_lane63(xcA);
        float sB = wave_sum_lane63(xcB);
        if (lane == 63) {
            Shalf[0][0][w] = sA; Shalf[1][0][w] = sA;
            Shalf[0][1][w] = sB; Shalf[1][1][w] = sB;
        }
    }
    __syncthreads();                       // publish xbuf0 + Shalf

    // ---- 4-deep emit/mask slot pipeline per batch (vector loads, vmcnt-queued) ----
    float fA0, fA1, fA2, fA3, fB0, fB1, fB2, fB3;
    int   mA0, mA1, mA2, mA3, mB0, mB1, mB2, mB3;
#define PRELOAD(S, tt) { \
        int tq = ((tt) < L_) ? (tt) : (L_ - 1);          \
        fA##S = featA[tq * T_ + j];                      \
        fB##S = featB[tq * T_ + j];                      \
        int tqv = tq; asm("" : "+v"(tqv));               \
        mA##S = maskA[tqv];                              \
        int tqw = tq; asm("" : "+v"(tqw));               \
        mB##S = maskB[tqw]; }
    PRELOAD(0, 1) PRELOAD(1, 2) PRELOAD(2, 3) PRELOAD(3, 4)
#undef PRELOAD

    const float LOG128 = 4.8520302639196171f;
    int pr = 0;
    int t  = 1;

#define DOTQ2(k) { \
        u32x4 a4 = apA[(k)];                      \
        u32x4 b4 = apB[(k)];                      \
        aA0 = dot2_acc(ec_##k.x, a4.x, aA0);      \
        aB0 = dot2_acc(ec_##k.x, b4.x, aB0);      \
        aA1 = dot2_acc(ec_##k.y, a4.y, aA1);      \
        aB1 = dot2_acc(ec_##k.y, b4.y, aB1);      \
        aA2 = dot2_acc(ec_##k.z, a4.z, aA2);      \
        aB2 = dot2_acc(ec_##k.z, b4.z, aB2);      \
        aA3 = dot2_acc(ec_##k.w, a4.w, aA3);      \
        aB3 = dot2_acc(ec_##k.w, b4.w, aB3); }

#define STEP(S) { \
        const float fcA = fA##S;                              \
        const float fcB = fB##S;                              \
        const int   mcA = mA##S;                              \
        const int   mcB = mB##S;                              \
        const int tn = (t + 4 < L_) ? (t + 4) : (L_ - 1);     \
        fA##S = featA[tn * T_ + j];                           \
        fB##S = featB[tn * T_ + j];                           \
        int tnv = tn; asm("" : "+v"(tnv));                    \
        mA##S = maskA[tnv];                                   \
        int tnw = tn; asm("" : "+v"(tnw));                    \
        mB##S = maskB[tnw];                                   \
        const float2 shA = *(const float2*)&Shalf[t & 1][0][0]; \
        const float2 shB = *(const float2*)&Shalf[t & 1][1][0]; \
        const float exqA = __expf(fcA);                       \
        const float exqB = __expf(fcB);                       \
        float aA0 = 0.f, aA1 = 0.f, aA2 = 0.f, aA3 = 0.f;     \
        float aB0 = 0.f, aB1 = 0.f, aB2 = 0.f, aB3 = 0.f;     \
        const u32x4* apA = (const u32x4*)xbuf[pr][0];         \
        const u32x4* apB = (const u32x4*)xbuf[pr][1];         \
        DOTQ2(0)  DOTQ2(1)  DOTQ2(2)  DOTQ2(3)                \
        DOTQ2(4)  DOTQ2(5)  DOTQ2(6)  DOTQ2(7)                \
        DOTQ2(8)  DOTQ2(9)  DOTQ2(10) DOTQ2(11)               \
        DOTQ2(12) DOTQ2(13) DOTQ2(14) DOTQ2(15)               \
        const float ssA = (aA0 + aA1) + (aA2 + aA3);          \
        const float ssB = (aB0 + aB1) + (aB2 + aB3);          \
        const float StA = shA.x + shA.y;                      \
        const float StB = shB.x + shB.y;                      \
        const float rcA = 1.0f / (StA * 128.0f);              \
        const float rcB = 1.0f / (StB * 128.0f);              \
        const float lcA = __logf(StA) + LOG128;               \
        const float lcB = __logf(StB) + LOG128;               \
        const float xA = ssA * exqA * rcA;                    \
        const float xB = ssB * exqB * rcB;                    \
        if (mcA) { xcA = xA; NA += lcA; }                     \
        if (mcB) { xcB = xB; NB += lcB; }                     \
        xbuf[pr ^ 1][0][j] = __float2half(xcA);               \
        xbuf[pr ^ 1][1][j] = __float2half(xcB);               \
        float slA = wave_sum_lane63(xcA);                     \
        float slB = wave_sum_lane63(xcB);                     \
        if (lane == 63) {                                     \
            Shalf[(t + 1) & 1][0][w] = slA;                   \
            Shalf[(t + 1) & 1][1][w] = slB;                   \
        }                                                     \
        asm volatile("s_waitcnt lgkmcnt(0)" ::: "memory");    \
        __builtin_amdgcn_s_barrier();                         \
        __builtin_amdgcn_sched_barrier(0);                    \
        pr ^= 1; ++t;                                         \
    }

    // 511 steps = 127 quads + 3
    for (int q = 0; q < 127; ++q) { STEP(0) STEP(1) STEP(2) STEP(3) }
    STEP(0) STEP(1) STEP(2)

#undef STEP
#undef DOTQ2

    // ---- norms (final Shalf written to buf (511+1)&1 = 0) ----
    const float2 shFA = *(const float2*)&Shalf[0][0][0];
    const float2 shFB = *(const float2*)&Shalf[0][1][0];
    const float normA = NA + __logf(shFA.x + shFA.y);
    const float normB = NB + __logf(shFB.x + shFB.y);

    // ---- gold path score: wave w handles batch w of this block ----
    const float* featW = (w == 0) ? featA : featB;
    const int*   maskW = (w == 0) ? maskA : maskB;
    const int*   tagW  = tags + (bA + w) * L_;
    float g = 0.f;
    for (int tt = lane; tt < L_; tt += 64) {
        int tg = tagW[tt];
        g += featW[tt * T_ + tg] * (float)maskW[tt];
        if (tt + 1 < L_) {
            g += trans[tg * T_ + tagW[tt + 1]] * (float)maskW[tt + 1];
        }
    }
    #pragma unroll
    for (int off = 32; off >= 1; off >>= 1) g += __shfl_xor(g, off);
    if (lane == 0) redx[4 + w] = g;
    __syncthreads();

    if (tid == 0) {
        out[bA] = normA - redx[4];
        out[bB] = normB - redx[5];
    }
}

extern "C" void kernel_launch(void* const* d_in, const int* in_sizes, int n_in,
                              void* d_out, int out_size, void* d_ws, size_t ws_size,
                              hipStream_t stream) {
    const float* feats = (const float*)d_in[0];
    const float* trans = (const float*)d_in[1];
    const int*   tags  = (const int*)d_in[2];
    const int*   mask  = (const int*)d_in[3];
    float* out = (float*)d_out;

    crf_nll_kernel<<<B_ / 2, NTHR, 0, stream>>>(feats, trans, tags, mask, out);
}